// Round 2
// baseline (6123.954 us; speedup 1.0000x reference)
//
#include <hip/hip_runtime.h>
#include <hip/hip_bf16.h>
#include <cstddef>

typedef __bf16 bf16_t;
typedef bf16_t bf16x8 __attribute__((ext_vector_type(8)));
typedef bf16_t bf16x4 __attribute__((ext_vector_type(4)));
typedef float  f32x4  __attribute__((ext_vector_type(4)));
typedef unsigned u32x4 __attribute__((ext_vector_type(4)));
typedef unsigned u32x2 __attribute__((ext_vector_type(2)));

#define T_STEPS 256
#define BATCH   32
#define HDIM    1024
#define ZDIM    4096

// ---------------- workspace sizes ----------------
constexpr size_t SZ_HSEQ  = (size_t)8192 * 1024 * 2;      // 16 MiB (hi or lo)
constexpr size_t SZ_CSG   = (size_t)2 * 32 * 1024 * 2 * 4; // 512 KiB tagged {c,sg} fp32 pairs
constexpr size_t SZ_HST   = (size_t)32 * 1024 * 2;        // 64 KiB (hi or lo)
constexpr size_t SZ_CST   = (size_t)32 * 1024 * 4;        // 128 KiB
constexpr size_t SZ_MU    = 256;
constexpr size_t SZ_TAIL  = SZ_CSG + 2*SZ_HST + SZ_CST + SZ_MU;
constexpr int    FILL_WORDS = (int)(SZ_CSG / 4);

// ---------------- LDS ----------------
constexpr int SLAB_STRIDE = 264;                 // W staging rows (bf16)
constexpr int HL_STRIDE   = 1040;                // h rows (bf16), 2080 B
// post-staging: hl_hi [8][1040] @0, hl_lo @16640, sredw[4][8][2] @33280
constexpr int SCAN_LDS    = 2 * 64 * SLAB_STRIDE * 2;  // 67584

__global__ void init_fill(unsigned* __restrict__ p, int n) {
    int i = blockIdx.x * blockDim.x + threadIdx.x;
    if (i < n) p[i] = 0xFFFFFFFFu;   // tag bits = 3: never matches t=0/1 polls
}

__device__ __forceinline__ void split_bf16(float v, bf16_t& hi, bf16_t& lo) {
    hi = (bf16_t)v;
    lo = (bf16_t)(v - (float)hi);
}
__device__ __forceinline__ float tanh_fast(float x) {
    float e = __expf(2.f * x);
    return 1.f - 2.f * __builtin_amdgcn_rcpf(e + 1.f);
}
__device__ __forceinline__ void bar_lds() {
    asm volatile("s_waitcnt lgkmcnt(0)" ::: "memory");
    __builtin_amdgcn_s_barrier();
    asm volatile("" ::: "memory");
}

// ---------------- input-projection GEMM (split-precision bf16x2) ----------------
// MODE 0: A fp32 with series row-remap (layer0, K=256)
// MODE 1: A pre-split hi/lo bf16 (layer1, K=1024)
template<int KTOT, int MODE>
__global__ __launch_bounds__(256) void gemm_xp(
    const float*  __restrict__ Afp,
    const bf16_t* __restrict__ Ahi,
    const bf16_t* __restrict__ Alo,
    const float*  __restrict__ W,
    const float*  __restrict__ bias,
    float*        __restrict__ xp,
    int t0)
{
    __shared__ bf16_t Ash[64][40], Asl[64][40], Bsh[64][40], Bsl[64][40];
    const int bm = blockIdx.x / (ZDIM/64);
    const int bn = blockIdx.x % (ZDIM/64);
    const int tid  = threadIdx.x;
    const int lane = tid & 63;
    const int w    = tid >> 6;
    const int wm = w >> 1, wn = w & 1;
    const int q   = lane >> 4;
    const int l15 = lane & 15;

    f32x4 acc[2][2] = {};

    const int sm = tid & 63;
    const int sk = (tid >> 6) * 8;
    const int gr = t0*32 + bm*64 + sm;
    const float*  Arow  = nullptr;
    const bf16_t* Ahrow = nullptr;
    const bf16_t* Alrow = nullptr;
    if constexpr (MODE == 0) {
        int tt = gr >> 5, bb = gr & 31;
        Arow = Afp + ((size_t)bb * T_STEPS + tt) * 256;
    } else {
        Ahrow = Ahi + (size_t)gr * HDIM;
        Alrow = Alo + (size_t)gr * HDIM;
    }
    const int gcol = bn*64 + sm;

    for (int k0 = 0; k0 < KTOT; k0 += 32) {
        if constexpr (MODE == 0) {
            f32x4 a0 = *(const f32x4*)(Arow + k0 + sk);
            f32x4 a1 = *(const f32x4*)(Arow + k0 + sk + 4);
            #pragma unroll
            for (int j = 0; j < 4; ++j) {
                split_bf16(a0[j], Ash[sm][sk+j],   Asl[sm][sk+j]);
                split_bf16(a1[j], Ash[sm][sk+4+j], Asl[sm][sk+4+j]);
            }
        } else {
            *(bf16x8*)&Ash[sm][sk] = *(const bf16x8*)(Ahrow + k0 + sk);
            *(bf16x8*)&Asl[sm][sk] = *(const bf16x8*)(Alrow + k0 + sk);
        }
        #pragma unroll
        for (int j = 0; j < 8; ++j) {
            float wv = W[(size_t)(k0 + sk + j) * ZDIM + gcol];
            split_bf16(wv, Bsh[sm][sk+j], Bsl[sm][sk+j]);
        }
        __syncthreads();
        #pragma unroll
        for (int mt = 0; mt < 2; ++mt) {
            #pragma unroll
            for (int nt = 0; nt < 2; ++nt) {
                bf16x8 ah = *(const bf16x8*)&Ash[wm*32 + mt*16 + l15][q*8];
                bf16x8 al = *(const bf16x8*)&Asl[wm*32 + mt*16 + l15][q*8];
                bf16x8 bh = *(const bf16x8*)&Bsh[wn*32 + nt*16 + l15][q*8];
                bf16x8 bl = *(const bf16x8*)&Bsl[wn*32 + nt*16 + l15][q*8];
                acc[mt][nt] = __builtin_amdgcn_mfma_f32_16x16x32_bf16(ah, bh, acc[mt][nt], 0, 0, 0);
                acc[mt][nt] = __builtin_amdgcn_mfma_f32_16x16x32_bf16(al, bh, acc[mt][nt], 0, 0, 0);
                acc[mt][nt] = __builtin_amdgcn_mfma_f32_16x16x32_bf16(ah, bl, acc[mt][nt], 0, 0, 0);
            }
        }
        __syncthreads();
    }
    #pragma unroll
    for (int mt = 0; mt < 2; ++mt) {
        int row = bm*64 + wm*32 + mt*16 + q*4;
        #pragma unroll
        for (int nt = 0; nt < 2; ++nt) {
            int col = bn*64 + wn*32 + nt*16 + l15;
            float bia = bias[col];
            #pragma unroll
            for (int r = 0; r < 4; ++r)
                xp[(size_t)(row + r)*ZDIM + col] = acc[mt][nt][r] + bia;
        }
    }
}

// ---------------- persistent recurrent scan: ONE tagged rendezvous per step ------
// grid 256 x 256. group gid=blk>>6 owns batches 8*gid..+7; block lid=blk&63 owns
// h-cols H0=lid*16 for the MFMA/publish. W in register hi/lo bf16 A-fragments.
// Per step: MFMA -> gates -> publish tagged {c_f32,sg_f32} pair (8B, tag = t&3 in
// the 2 mantissa LSBs of EACH dword; self-validating, so no drain/flags/ordering)
// -> s_sleep-backoff poll of all 8 rows x 1024 cols -> redundant block-local LN
// stats (64-lane butterfly + cross-wave LDS) -> LN + h computed locally for all
// 8x1024 -> pack hi/lo into LDS. ONE MALL hop per step (round-1 had two).
// Skew between blocks is bounded to 1 step (a block can't pass step t until all
// published step t), so parity slots + 2-bit tags can never alias.
__global__ __launch_bounds__(256, 1) void scan_kernel(
    const float* __restrict__ Wh,      // [1024][4096] fp32 recurrent rows
    const float* __restrict__ xp,      // [cT*32][4096] fp32 x-proj (incl bias)
    const float* __restrict__ gamma,
    const float* __restrict__ beta,
    unsigned*    Csg,                  // [2][32][1024][2] tagged {c,sg} fp32
    bf16_t*      __restrict__ hseq_hi, // [T*32][1024] or null (layer0)
    bf16_t*      __restrict__ hseq_lo,
    float*       __restrict__ outlast, // [32][1024] or null (layer1)
    bf16_t*      __restrict__ hst_hi,  // [32][1024] chunk-carry
    bf16_t*      __restrict__ hst_lo,
    float*       __restrict__ cstate,  // [32][1024]
    float*       __restrict__ mustate, // [32]
    int t0, int t1)
{
    extern __shared__ char smem[];
    bf16_t* slab_hi = (bf16_t*)smem;                       // W staging
    bf16_t* slab_lo = (bf16_t*)(smem + 64*SLAB_STRIDE*2);
    bf16_t* hl_hi   = (bf16_t*)smem;                       // [8][1040] post-staging
    bf16_t* hl_lo   = (bf16_t*)(smem + 8*HL_STRIDE*2);
    float*  sredw   = (float*)(smem + 16*HL_STRIDE*2);     // [4 waves][8 batch][2]

    const int gid = blockIdx.x >> 6;
    const int lid = blockIdx.x & 63;
    const int B0  = gid * 8;
    const int H0  = lid * 16;
    const int tid  = threadIdx.x;
    const int lane = tid & 63;
    const int w    = tid >> 6;
    const int q    = lane >> 4;
    const int l15  = lane & 15;

    // ---- stage recurrent W slice -> registers (hi/lo A-fragments) via LDS slabs
    bf16x8 wf_hi[32], wf_lo[32];
    {
        const int kw   = tid >> 6;
        const int strip= (tid >> 4) & 3;
        const int col  = tid & 15;
        const int gc2  = strip*1024 + H0 + col;
        const int rr_w = col*4 + strip;
        #pragma unroll
        for (int s = 0; s < 4; ++s) {
            for (int j = 0; j < 64; ++j) {
                int kk = j*4 + kw;
                float v = Wh[(size_t)(s*256 + kk)*ZDIM + gc2];
                bf16_t hi, lo; split_bf16(v, hi, lo);
                slab_hi[rr_w*SLAB_STRIDE + kk] = hi;
                slab_lo[rr_w*SLAB_STRIDE + kk] = lo;
            }
            __syncthreads();
            #pragma unroll
            for (int kbl = 0; kbl < 8; ++kbl) {
                wf_hi[s*8+kbl] = *(const bf16x8*)&slab_hi[(16*w + l15)*SLAB_STRIDE + kbl*32 + q*8];
                wf_lo[s*8+kbl] = *(const bf16x8*)&slab_lo[(16*w + l15)*SLAB_STRIDE + kbl*32 + q*8];
            }
            __syncthreads();
        }
    }

    // owner identity (MFMA C map)
    const int  bidx  = l15;
    const bool valid = bidx < 8;
    const int  batch = B0 + bidx;
    const int  hcl   = 4*w + q;
    const int  hcg   = H0 + hcl;
    const size_t xpbase = (size_t)batch * ZDIM + (size_t)H0 + hcl;
    const int hrow  = (l15 < 8) ? l15 : 7;

    // staging identity: thread owns cols cb..cb+3 for all 8 group rows
    const int cb = tid * 4;
    const f32x4 g_s = *(const f32x4*)&gamma[cb];
    const f32x4 b_s = *(const f32x4*)&beta[cb];

    float c = 0.f;
    float mu_row[8] = {0.f,0.f,0.f,0.f,0.f,0.f,0.f,0.f};
    if (t0 > 0) {
        if (valid) c = cstate[(size_t)batch*HDIM + hcg];
        #pragma unroll
        for (int r = 0; r < 8; ++r) {
            mu_row[r] = mustate[B0 + r];
            *(bf16x4*)&hl_hi[r*HL_STRIDE + cb] = *(const bf16x4*)&hst_hi[(size_t)(B0+r)*HDIM + cb];
            *(bf16x4*)&hl_lo[r*HL_STRIDE + cb] = *(const bf16x4*)&hst_lo[(size_t)(B0+r)*HDIM + cb];
        }
    }
    __syncthreads();

    // preload xp for first step
    float xpv[4] = {0.f, 0.f, 0.f, 0.f};
    if (valid) {
        const float* xpt = xp + xpbase;
        #pragma unroll
        for (int r = 0; r < 4; ++r) xpv[r] = xpt[(size_t)r * 1024];
    }

    const bool is_l0 = (hseq_hi != nullptr);
    // poll base (u32x4 units): thread's 32B slice (4 cols x {c,sg}) of row 0
    volatile const u32x4* csb;

    #pragma unroll 1
    for (int t = t0; t < t1; ++t) {
        f32x4 acc_hh = {0.f,0.f,0.f,0.f}, acc_lh = acc_hh, acc_hl = acc_hh;
        if (t > 0) {
            const bf16_t* Bh = hl_hi + (size_t)hrow * HL_STRIDE + q*8;
            const bf16_t* Bl = hl_lo + (size_t)hrow * HL_STRIDE + q*8;
            #pragma unroll
            for (int kb = 0; kb < 32; ++kb) {
                bf16x8 bh = *(const bf16x8*)(Bh + kb*32);
                bf16x8 bv = *(const bf16x8*)(Bl + kb*32);
                acc_hh = __builtin_amdgcn_mfma_f32_16x16x32_bf16(wf_hi[kb], bh, acc_hh, 0, 0, 0);
                acc_lh = __builtin_amdgcn_mfma_f32_16x16x32_bf16(wf_lo[kb], bh, acc_lh, 0, 0, 0);
                acc_hl = __builtin_amdgcn_mfma_f32_16x16x32_bf16(wf_hi[kb], bv, acc_hl, 0, 0, 0);
            }
        }
        float z[4];
        #pragma unroll
        for (int r = 0; r < 4; ++r)
            z[r] = ((acc_lh[r] + acc_hl[r]) + acc_hh[r]) + xpv[r];

        float zi = fminf(fmaxf(z[0], -6.f), 3.f);
        float zf = fminf(fmaxf(z[1], -6.f), 3.f);
        float ig = __expf(zi);
        float fg = __expf(zf);
        float cand = tanh_fast(z[2]);
        float sg = 1.f / (1.f + __expf(-z[3]));
        c = fg * c + ig * cand;

        const int par = t & 1;
        const unsigned tg = (unsigned)(t & 3);

        // ---- publish tagged {c, sg} immediately (nothing else on the path)
        if (valid) {
            u32x2 pk;
            pk[0] = (__float_as_uint(c)  & ~3u) | tg;   // 2 LSB mantissa -> tag (err 2^-21)
            pk[1] = (__float_as_uint(sg) & ~3u) | tg;
            *(volatile u32x2*)(Csg + (((size_t)par*32 + batch)*HDIM + hcg)*2) = pk;
        }

        // xp prefetch for t+1: issued now, flies through poll + LN
        if (valid && t+1 < t1) {
            const float* xpt = xp + (size_t)(t+1 - t0) * (BATCH*ZDIM) + xpbase;
            #pragma unroll
            for (int r = 0; r < 4; ++r) xpv[r] = xpt[(size_t)r * 1024];
        }

        // ---- single rendezvous: poll all 8 rows x own 4 cols (self-validating)
        csb = (volatile const u32x4*)(Csg + ((size_t)par*32 + B0)*HDIM*2) + (size_t)tid*2;
        u32x4 uu0[8], uu1[8];
        #pragma unroll
        for (int r = 0; r < 8; ++r) { uu0[r] = csb[(size_t)r*512]; uu1[r] = csb[(size_t)r*512 + 1]; }
        bool all_ok = false;
        while (!all_ok) {
            all_ok = true;
            #pragma unroll
            for (int r = 0; r < 8; ++r) {
                unsigned m = ((uu0[r][0]^tg)|(uu0[r][1]^tg)|(uu0[r][2]^tg)|(uu0[r][3]^tg)
                             |(uu1[r][0]^tg)|(uu1[r][1]^tg)|(uu1[r][2]^tg)|(uu1[r][3]^tg)) & 3u;
                if (m) {
                    uu0[r] = csb[(size_t)r*512];
                    uu1[r] = csb[(size_t)r*512 + 1];
                    all_ok = false;
                }
            }
            if (!all_ok) __builtin_amdgcn_s_sleep(1);   // backoff: let straggler stores land
        }

        // ---- block-local stats: per-thread partial -> 64-lane butterfly -> LDS
        float s1t[8], s2t[8];
        #pragma unroll
        for (int r = 0; r < 8; ++r) {
            float s1 = 0.f, s2 = 0.f;
            #pragma unroll
            for (int e = 0; e < 4; ++e) {
                unsigned cu = (e < 2) ? uu0[r][(e&1)*2] : uu1[r][(e&1)*2];
                float dm = __uint_as_float(cu & ~3u) - mu_row[r];
                s1 += dm; s2 += dm*dm;
            }
            #pragma unroll
            for (int m = 1; m < 64; m <<= 1) {
                s1 += __shfl_xor(s1, m);
                s2 += __shfl_xor(s2, m);
            }
            s1t[r] = s1; s2t[r] = s2;
        }
        if (lane == 0) {
            #pragma unroll
            for (int r = 0; r < 8; ++r) {
                sredw[(w*8 + r)*2]     = s1t[r];
                sredw[(w*8 + r)*2 + 1] = s2t[r];
            }
        }
        bar_lds();   // B1: sredw ready

        // ---- LN + h for all 8 rows (every thread, its 4 cols)
        const bool carry = (t == t1-1) && (t1 < T_STEPS);
        #pragma unroll
        for (int r = 0; r < 8; ++r) {
            float S1 = sredw[(0*8+r)*2] + sredw[(1*8+r)*2]
                     + sredw[(2*8+r)*2] + sredw[(3*8+r)*2];
            float S2 = sredw[(0*8+r)*2+1] + sredw[(1*8+r)*2+1]
                     + sredw[(2*8+r)*2+1] + sredw[(3*8+r)*2+1];
            float dmu = S1 * (1.f/1024.f);
            float mu  = mu_row[r] + dmu;
            float var = S2 * (1.f/1024.f) - dmu*dmu;
            float rsig = rsqrtf(var + 1e-5f);
            mu_row[r] = mu;
            bf16x4 bh, blv;
            f32x4 hv4;
            #pragma unroll
            for (int e = 0; e < 4; ++e) {
                unsigned cu = (e < 2) ? uu0[r][(e&1)*2]     : uu1[r][(e&1)*2];
                unsigned su = (e < 2) ? uu0[r][(e&1)*2 + 1] : uu1[r][(e&1)*2 + 1];
                float cv  = __uint_as_float(cu & ~3u);
                float sgv = __uint_as_float(su & ~3u);
                float ln  = (cv - mu) * rsig * g_s[e] + b_s[e];
                float h   = sgv * tanh_fast(ln);
                hv4[e] = h;
                bf16_t hi, lo; split_bf16(h, hi, lo);
                bh[e] = hi; blv[e] = lo;
            }
            *(bf16x4*)&hl_hi[r*HL_STRIDE + cb] = bh;
            *(bf16x4*)&hl_lo[r*HL_STRIDE + cb] = blv;
            if (is_l0 && lid == r) {
                *(bf16x4*)&hseq_hi[((size_t)t*32 + B0 + r)*HDIM + cb] = bh;
                *(bf16x4*)&hseq_lo[((size_t)t*32 + B0 + r)*HDIM + cb] = blv;
            }
            if (carry && lid == r) {
                *(bf16x4*)&hst_hi[(size_t)(B0+r)*HDIM + cb] = bh;
                *(bf16x4*)&hst_lo[(size_t)(B0+r)*HDIM + cb] = blv;
            }
            if (outlast && t == T_STEPS-1 && lid == r)
                *(f32x4*)&outlast[(size_t)(B0+r)*HDIM + cb] = hv4;
        }
        bar_lds();   // B2: hl ready for next step's MFMA (hseq stores fly)
    }

    // chunk-carry state
    if (t1 < T_STEPS) {
        if (valid) cstate[(size_t)batch*HDIM + hcg] = c;
        if (lid == 0 && tid == 0) {
            #pragma unroll
            for (int r = 0; r < 8; ++r) mustate[B0 + r] = mu_row[r];
        }
    }
}

extern "C" void kernel_launch(void* const* d_in, const int* in_sizes, int n_in,
                              void* d_out, int out_size, void* d_ws, size_t ws_size,
                              hipStream_t stream) {
    (void)in_sizes; (void)n_in;
    const float* series = (const float*)d_in[0];
    const float* W0  = (const float*)d_in[1];
    const float* b0  = (const float*)d_in[2];
    const float* g0  = (const float*)d_in[3];
    const float* be0 = (const float*)d_in[4];
    const float* W1  = (const float*)d_in[5];
    const float* b1  = (const float*)d_in[6];
    const float* g1  = (const float*)d_in[7];
    const float* be1 = (const float*)d_in[8];
    float* out = (float*)d_out;
    unsigned char* ws = (unsigned char*)d_ws;

    int cT = 0;
    const int cands[4] = {256, 128, 64, 32};
    for (int i = 0; i < 4; ++i) {
        size_t need = (size_t)cands[i]*32*ZDIM*4 + 2*SZ_HSEQ + SZ_TAIL;
        if (need <= ws_size) { cT = cands[i]; break; }
    }
    if (cT == 0) {
        (void)hipMemsetAsync(d_out, 0, (size_t)out_size * sizeof(float), stream);
        return;
    }
    const size_t sz_xp = (size_t)cT*32*ZDIM*4;
    unsigned char* p = ws;
    float*    xp      = (float*)p;    p += sz_xp;
    bf16_t*   hseq_hi = (bf16_t*)p;   p += SZ_HSEQ;
    bf16_t*   hseq_lo = (bf16_t*)p;   p += SZ_HSEQ;
    unsigned* Csg     = (unsigned*)p; p += SZ_CSG;
    bf16_t*   hst_hi  = (bf16_t*)p;   p += SZ_HST;
    bf16_t*   hst_lo  = (bf16_t*)p;   p += SZ_HST;
    float*    cstate  = (float*)p;    p += SZ_CST;
    float*    mustate = (float*)p;

    (void)hipFuncSetAttribute((const void*)scan_kernel,
                              hipFuncAttributeMaxDynamicSharedMemorySize, SCAN_LDS);

    init_fill<<<(FILL_WORDS + 255)/256, 256, 0, stream>>>(Csg, FILL_WORDS);

    const int nch = T_STEPS / cT;
    const int gemm_grid = (cT*32/64) * (ZDIM/64);

    // ---- layer 0 ----
    for (int ci = 0; ci < nch; ++ci) {
        int t0 = ci*cT, t1 = t0 + cT;
        gemm_xp<256, 0><<<gemm_grid, 256, 0, stream>>>(
            series, nullptr, nullptr, W0, b0, xp, t0);
        scan_kernel<<<256, 256, SCAN_LDS, stream>>>(
            W0 + (size_t)256*ZDIM, xp, g0, be0, Csg,
            hseq_hi, hseq_lo, nullptr, hst_hi, hst_lo, cstate, mustate, t0, t1);
    }
    // ---- layer 1 ----
    for (int ci = 0; ci < nch; ++ci) {
        int t0 = ci*cT, t1 = t0 + cT;
        gemm_xp<1024, 1><<<gemm_grid, 256, 0, stream>>>(
            nullptr, hseq_hi, hseq_lo, W1, b1, xp, t0);
        scan_kernel<<<256, 256, SCAN_LDS, stream>>>(
            W1 + (size_t)1024*ZDIM, xp, g1, be1, Csg,
            nullptr, nullptr, out, hst_hi, hst_lo, cstate, mustate, t0, t1);
    }
}

// Round 3
// 4171.718 us; speedup vs baseline: 1.4680x; 1.4680x over previous
//
#include <hip/hip_runtime.h>
#include <hip/hip_bf16.h>
#include <cstddef>

typedef __bf16 bf16_t;
typedef _Float16 f16_t;
typedef bf16_t bf16x8 __attribute__((ext_vector_type(8)));
typedef bf16_t bf16x4 __attribute__((ext_vector_type(4)));
typedef f16_t  f16x8  __attribute__((ext_vector_type(8)));
typedef float  f32x4  __attribute__((ext_vector_type(4)));
typedef unsigned u32x4 __attribute__((ext_vector_type(4)));
typedef unsigned u32x2 __attribute__((ext_vector_type(2)));

#define T_STEPS 256
#define BATCH   32
#define HDIM    1024
#define ZDIM    4096

// ---------------- workspace sizes ----------------
constexpr size_t SZ_HSEQ  = (size_t)8192 * 1024 * 2;      // 16 MiB (hi or lo)
constexpr size_t SZ_HBUF  = (size_t)2 * 32 * 512 * 4;     // 128 KiB tagged fp16-pair h dwords
constexpr size_t SZ_SP    = (size_t)2 * 4 * 8 * 128 * 4;  // 32 KiB tagged LN partials
constexpr size_t SZ_HST   = (size_t)32 * 1024 * 2;        // 64 KiB (hi or lo)
constexpr size_t SZ_CST   = (size_t)32 * 1024 * 4;        // 128 KiB
constexpr size_t SZ_MU    = 256;
constexpr size_t SZ_TAIL  = SZ_HBUF + SZ_SP + 2*SZ_HST + SZ_CST + SZ_MU;
constexpr int    FILL_WORDS = (int)((SZ_HBUF + SZ_SP) / 4);

// ---------------- LDS ----------------
constexpr int SLAB_STRIDE = 264;                 // W staging rows (fp16)
constexpr int HL_STRIDE   = 1040;                // h rows (fp16), 2080 B
// post-staging: hl [8][1040] fp16 @0, swred[4][8][2] @16640, sredS[8][2] after
constexpr int SCAN_LDS    = 2 * 64 * SLAB_STRIDE * 2;  // 67584 (staging dominates)

__global__ void init_fill(unsigned* __restrict__ p, int n) {
    int i = blockIdx.x * blockDim.x + threadIdx.x;
    if (i < n) p[i] = 0xFFFFFFFFu;   // poison: tag never matches t=0/1 polls
}

__device__ __forceinline__ void split_bf16(float v, bf16_t& hi, bf16_t& lo) {
    hi = (bf16_t)v;
    lo = (bf16_t)(v - (float)hi);
}
__device__ __forceinline__ unsigned short f16_bits(f16_t f) {
    union { unsigned short u; f16_t f2; } x; x.f2 = f; return x.u;
}
__device__ __forceinline__ float tanh_fast(float x) {
    float e = __expf(2.f * x);
    return 1.f - 2.f * __builtin_amdgcn_rcpf(e + 1.f);
}
__device__ __forceinline__ void bar_lds() {
    asm volatile("s_waitcnt lgkmcnt(0)" ::: "memory");
    __builtin_amdgcn_s_barrier();
    asm volatile("" ::: "memory");
}

// ---------------- input-projection GEMM (split-precision bf16x2, UNCHANGED) -----
template<int KTOT, int MODE>
__global__ __launch_bounds__(256) void gemm_xp(
    const float*  __restrict__ Afp,
    const bf16_t* __restrict__ Ahi,
    const bf16_t* __restrict__ Alo,
    const float*  __restrict__ W,
    const float*  __restrict__ bias,
    float*        __restrict__ xp,
    int t0)
{
    __shared__ bf16_t Ash[64][40], Asl[64][40], Bsh[64][40], Bsl[64][40];
    const int bm = blockIdx.x / (ZDIM/64);
    const int bn = blockIdx.x % (ZDIM/64);
    const int tid  = threadIdx.x;
    const int lane = tid & 63;
    const int w    = tid >> 6;
    const int wm = w >> 1, wn = w & 1;
    const int q   = lane >> 4;
    const int l15 = lane & 15;

    f32x4 acc[2][2] = {};

    const int sm = tid & 63;
    const int sk = (tid >> 6) * 8;
    const int gr = t0*32 + bm*64 + sm;
    const float*  Arow  = nullptr;
    const bf16_t* Ahrow = nullptr;
    const bf16_t* Alrow = nullptr;
    if constexpr (MODE == 0) {
        int tt = gr >> 5, bb = gr & 31;
        Arow = Afp + ((size_t)bb * T_STEPS + tt) * 256;
    } else {
        Ahrow = Ahi + (size_t)gr * HDIM;
        Alrow = Alo + (size_t)gr * HDIM;
    }
    const int gcol = bn*64 + sm;

    for (int k0 = 0; k0 < KTOT; k0 += 32) {
        if constexpr (MODE == 0) {
            f32x4 a0 = *(const f32x4*)(Arow + k0 + sk);
            f32x4 a1 = *(const f32x4*)(Arow + k0 + sk + 4);
            #pragma unroll
            for (int j = 0; j < 4; ++j) {
                split_bf16(a0[j], Ash[sm][sk+j],   Asl[sm][sk+j]);
                split_bf16(a1[j], Ash[sm][sk+4+j], Asl[sm][sk+4+j]);
            }
        } else {
            *(bf16x8*)&Ash[sm][sk] = *(const bf16x8*)(Ahrow + k0 + sk);
            *(bf16x8*)&Asl[sm][sk] = *(const bf16x8*)(Alrow + k0 + sk);
        }
        #pragma unroll
        for (int j = 0; j < 8; ++j) {
            float wv = W[(size_t)(k0 + sk + j) * ZDIM + gcol];
            split_bf16(wv, Bsh[sm][sk+j], Bsl[sm][sk+j]);
        }
        __syncthreads();
        #pragma unroll
        for (int mt = 0; mt < 2; ++mt) {
            #pragma unroll
            for (int nt = 0; nt < 2; ++nt) {
                bf16x8 ah = *(const bf16x8*)&Ash[wm*32 + mt*16 + l15][q*8];
                bf16x8 al = *(const bf16x8*)&Asl[wm*32 + mt*16 + l15][q*8];
                bf16x8 bh = *(const bf16x8*)&Bsh[wn*32 + nt*16 + l15][q*8];
                bf16x8 bl = *(const bf16x8*)&Bsl[wn*32 + nt*16 + l15][q*8];
                acc[mt][nt] = __builtin_amdgcn_mfma_f32_16x16x32_bf16(ah, bh, acc[mt][nt], 0, 0, 0);
                acc[mt][nt] = __builtin_amdgcn_mfma_f32_16x16x32_bf16(al, bh, acc[mt][nt], 0, 0, 0);
                acc[mt][nt] = __builtin_amdgcn_mfma_f32_16x16x32_bf16(ah, bl, acc[mt][nt], 0, 0, 0);
            }
        }
        __syncthreads();
    }
    #pragma unroll
    for (int mt = 0; mt < 2; ++mt) {
        int row = bm*64 + wm*32 + mt*16 + q*4;
        #pragma unroll
        for (int nt = 0; nt < 2; ++nt) {
            int col = bn*64 + wn*32 + nt*16 + l15;
            float bia = bias[col];
            #pragma unroll
            for (int r = 0; r < 4; ++r)
                xp[(size_t)(row + r)*ZDIM + col] = acc[mt][nt][r] + bia;
        }
    }
}

// ---------------- persistent recurrent scan: 2-hop, fp16 h broadcast -------------
// grid 256 x 256. group gid=blk>>6 owns batches 8*gid..+7; block lid=blk&63 owns
// h-cols H0=lid*16. W_rec in registers as fp16 hi + fp16 lo*2048 A-fragments
// (err 2^-24) -> 2 MFMA chains instead of 3.
// Per step: MFMA(f16) -> gates -> hop1: block LN partials tagged (t&3 in 2 fp32
// mantissa LSBs) -> poll 64 blocks -> butterfly -> owner computes LN + exact h
// (writes hseq/hst/outlast from fp32) -> hop2: publish h~ as {h0,h1} fp16 pairs,
// 1 tag bit per fp16 LSB (h err <= 1 ulp ~ 2^-11) -> wave-row poll 16KB/block ->
// unpack straight into fp16 LDS. Poll volume 36KB -> 20KB/block/step.
// Re-poison between layers fixes the cross-layer tag alias (layer1 t=2,3 vs
// layer0 t=254,255); within a layer skew<=1 step so parity+2-bit tags are safe.
__global__ __launch_bounds__(256, 1) void scan_kernel(
    const float* __restrict__ Wh,      // [1024][4096] fp32 recurrent rows
    const float* __restrict__ xp,      // [cT*32][4096] fp32 x-proj (incl bias)
    const float* __restrict__ gamma,
    const float* __restrict__ beta,
    unsigned*    Hbuf,                 // [2][32][512] tagged fp16-pair h dwords
    unsigned*    Sp,                   // [2][4][8][128] tagged LN partials
    bf16_t*      __restrict__ hseq_hi, // [T*32][1024] or null (layer0)
    bf16_t*      __restrict__ hseq_lo,
    float*       __restrict__ outlast, // [32][1024] or null (layer1)
    bf16_t*      __restrict__ hst_hi,  // [32][1024] chunk-carry
    bf16_t*      __restrict__ hst_lo,
    float*       __restrict__ cstate,  // [32][1024]
    float*       __restrict__ mustate, // [32]
    int t0, int t1)
{
    extern __shared__ char smem[];
    f16_t* slab_hi = (f16_t*)smem;                        // W staging
    f16_t* slab_lo = (f16_t*)(smem + 64*SLAB_STRIDE*2);
    f16_t* hl      = (f16_t*)smem;                        // [8][1040] fp16 post-staging
    float* swred   = (float*)(smem + 8*HL_STRIDE*2);      // [4 waves][8 batch][2]
    float* sredS   = swred + 64;                          // [8 batch][2]

    const int gid = blockIdx.x >> 6;
    const int lid = blockIdx.x & 63;
    const int B0  = gid * 8;
    const int H0  = lid * 16;
    const int tid  = threadIdx.x;
    const int lane = tid & 63;
    const int w    = tid >> 6;
    const int q    = lane >> 4;
    const int l15  = lane & 15;

    // ---- stage recurrent W slice -> registers (fp16 hi + fp16 lo*2048)
    f16x8 wf_hi[32], wf_lo[32];
    {
        const int kw   = tid >> 6;
        const int strip= (tid >> 4) & 3;
        const int col  = tid & 15;
        const int gc2  = strip*1024 + H0 + col;
        const int rr_w = col*4 + strip;
        #pragma unroll
        for (int s = 0; s < 4; ++s) {
            for (int j = 0; j < 64; ++j) {
                int kk = j*4 + kw;
                float v = Wh[(size_t)(s*256 + kk)*ZDIM + gc2];
                f16_t hi = (f16_t)v;
                f16_t lo = (f16_t)((v - (float)hi) * 2048.f);
                slab_hi[rr_w*SLAB_STRIDE + kk] = hi;
                slab_lo[rr_w*SLAB_STRIDE + kk] = lo;
            }
            __syncthreads();
            #pragma unroll
            for (int kbl = 0; kbl < 8; ++kbl) {
                wf_hi[s*8+kbl] = *(const f16x8*)&slab_hi[(16*w + l15)*SLAB_STRIDE + kbl*32 + q*8];
                wf_lo[s*8+kbl] = *(const f16x8*)&slab_lo[(16*w + l15)*SLAB_STRIDE + kbl*32 + q*8];
            }
            __syncthreads();
        }
    }

    // owner identity (MFMA C map)
    const int  bidx  = l15;
    const bool valid = bidx < 8;
    const int  batch = B0 + bidx;
    const int  hcl   = 4*w + q;
    const int  hcg   = H0 + hcl;
    const size_t xpbase = (size_t)batch * ZDIM + (size_t)H0 + hcl;
    const int hrow  = (l15 < 8) ? l15 : 7;

    // hop2 reader identity: wave w + lane-half owns rows rr = 2w + half
    const int half   = lane >> 5;
    const int lane32 = lane & 31;
    const int rr     = 2*w + half;
    const int rbatch = B0 + rr;

    float g_own = 0.f, b_own = 0.f;
    if (valid) { g_own = gamma[hcg]; b_own = beta[hcg]; }

    float c = 0.f, mu_own = 0.f;
    if (t0 > 0) {
        if (valid) {
            c = cstate[(size_t)batch*HDIM + hcg];
            mu_own = mustate[batch];
        }
        const int cb = tid * 4;
        #pragma unroll
        for (int r = 0; r < 8; ++r) {
            bf16x4 vh = *(const bf16x4*)&hst_hi[(size_t)(B0+r)*HDIM + cb];
            bf16x4 vl = *(const bf16x4*)&hst_lo[(size_t)(B0+r)*HDIM + cb];
            #pragma unroll
            for (int e = 0; e < 4; ++e)
                hl[r*HL_STRIDE + cb + e] = (f16_t)((float)vh[e] + (float)vl[e]);
        }
    }
    __syncthreads();

    // preload xp for first step
    float xpv[4] = {0.f, 0.f, 0.f, 0.f};
    if (valid) {
        const float* xpt = xp + xpbase;
        #pragma unroll
        for (int r = 0; r < 4; ++r) xpv[r] = xpt[(size_t)r * 1024];
    }

    const bool is_l0 = (hseq_hi != nullptr);

    #pragma unroll 1
    for (int t = t0; t < t1; ++t) {
        f32x4 acc_hh = {0.f,0.f,0.f,0.f}, acc_lh = acc_hh;
        if (t > 0) {
            const f16_t* Bp = hl + (size_t)hrow * HL_STRIDE + q*8;
            #pragma unroll
            for (int kb = 0; kb < 32; ++kb) {
                f16x8 b = *(const f16x8*)(Bp + kb*32);
                acc_hh = __builtin_amdgcn_mfma_f32_16x16x32_f16(wf_hi[kb], b, acc_hh, 0, 0, 0);
                acc_lh = __builtin_amdgcn_mfma_f32_16x16x32_f16(wf_lo[kb], b, acc_lh, 0, 0, 0);
            }
        }
        float z[4];
        #pragma unroll
        for (int r = 0; r < 4; ++r)
            z[r] = (acc_hh[r] + acc_lh[r]*(1.f/2048.f)) + xpv[r];

        float zi = fminf(fmaxf(z[0], -6.f), 3.f);
        float zf = fminf(fmaxf(z[1], -6.f), 3.f);
        float ig = __expf(zi);
        float fg = __expf(zf);
        float cand = tanh_fast(z[2]);
        float sg = 1.f / (1.f + __expf(-z[3]));
        c = fg * c + ig * cand;

        const int par = t & 1;
        const unsigned tg = (unsigned)(t & 3);
        const unsigned tgpat = (unsigned)(t & 1) | (((unsigned)(t >> 1) & 1u) << 16);

        // ---- hop1: intra-block LN partials -> tagged publish
        float dm = valid ? (c - mu_own) : 0.f;
        float s1 = dm, s2 = dm*dm;
        s1 += __shfl_xor(s1, 16); s2 += __shfl_xor(s2, 16);
        s1 += __shfl_xor(s1, 32); s2 += __shfl_xor(s2, 32);
        if (lane < 8) { swred[(w*8+lane)*2] = s1; swred[(w*8+lane)*2+1] = s2; }
        bar_lds();   // B1: swred ready

        if (tid < 8) {
            float S1p = swred[tid*2]       + swred[(8+tid)*2]
                      + swred[(16+tid)*2]  + swred[(24+tid)*2];
            float S2p = swred[tid*2+1]     + swred[(8+tid)*2+1]
                      + swred[(16+tid)*2+1]+ swred[(24+tid)*2+1];
            u32x2 pk;
            pk[0] = (__float_as_uint(S1p) & ~3u) | tg;
            pk[1] = (__float_as_uint(S2p) & ~3u) | tg;
            *(volatile u32x2*)(Sp + (((size_t)par*4 + gid)*8 + tid)*128 + (size_t)lid*2) = pk;
        }

        // xp prefetch for t+1: flies through both polls
        if (valid && t+1 < t1) {
            const float* xpt = xp + (size_t)(t+1 - t0) * (BATCH*ZDIM) + xpbase;
            #pragma unroll
            for (int r = 0; r < 4; ++r) xpv[r] = xpt[(size_t)r * 1024];
        }

        // ---- poll partials (self-validating), 32-lane reduce per batch
        {
            const int prr = tid >> 5, jj = tid & 31;
            volatile const u32x4* spb =
                (volatile const u32x4*)(Sp + (((size_t)par*4 + gid)*8 + prr)*128 + (size_t)jj*4);
            u32x4 sv = *spb;
            while ((((sv[0]^tg)|(sv[1]^tg)|(sv[2]^tg)|(sv[3]^tg)) & 3u) != 0u) {
                __builtin_amdgcn_s_sleep(1);
                sv = *spb;
            }
            float s1p = __uint_as_float(sv[0] & ~3u) + __uint_as_float(sv[2] & ~3u);
            float s2p = __uint_as_float(sv[1] & ~3u) + __uint_as_float(sv[3] & ~3u);
            #pragma unroll
            for (int m = 1; m < 32; m <<= 1) {
                s1p += __shfl_xor(s1p, m);
                s2p += __shfl_xor(s2p, m);
            }
            if (jj == 0) { sredS[prr*2] = s1p; sredS[prr*2+1] = s2p; }
        }
        bar_lds();   // B2: sredS ready

        // ---- owner: LN + exact h; publish h~ fp16 pair (tag: 1 LSB per fp16)
        const bool carry = (t == t1-1) && (t1 < T_STEPS);
        unsigned hbs = 0;
        if (valid) {
            float S1 = sredS[bidx*2], S2 = sredS[bidx*2+1];
            float dmu = S1 * (1.f/1024.f);
            float mu  = mu_own + dmu;
            float var = S2 * (1.f/1024.f) - dmu*dmu;
            float rsig = rsqrtf(var + 1e-5f);
            mu_own = mu;
            float ln   = (c - mu) * rsig * g_own + b_own;
            float hval = sg * tanh_fast(ln);
            if (is_l0) {
                bf16_t hi, lo; split_bf16(hval, hi, lo);
                hseq_hi[((size_t)t*32 + batch)*HDIM + hcg] = hi;
                hseq_lo[((size_t)t*32 + batch)*HDIM + hcg] = lo;
            }
            if (carry) {
                bf16_t hi, lo; split_bf16(hval, hi, lo);
                hst_hi[(size_t)batch*HDIM + hcg] = hi;
                hst_lo[(size_t)batch*HDIM + hcg] = lo;
            }
            if (outlast && t == T_STEPS-1)
                outlast[(size_t)batch*HDIM + hcg] = hval;
            unsigned tb = (q & 1) ? ((unsigned)(t >> 1) & 1u) : ((unsigned)t & 1u);
            hbs = ((unsigned)f16_bits((f16_t)hval) & 0xFFFEu) | tb;
        }
        unsigned pb2 = __shfl_xor(hbs, 16);   // partner col's bits (q ^ 1)
        if (valid && !(q & 1)) {
            unsigned dw = hbs | (pb2 << 16);
            *(volatile unsigned*)(Hbuf + ((size_t)par*32 + batch)*512 + ((unsigned)hcg >> 1)) = dw;
        }

        // ---- hop2: wave-row poll of fp16 h pairs straight into LDS
        volatile const u32x4* hb4 =
            (volatile const u32x4*)(Hbuf + ((size_t)par*32 + rbatch)*512) + lane32;
        u32x4 pv[4];
        #pragma unroll
        for (int k = 0; k < 4; ++k) pv[k] = hb4[(size_t)k*32];
        for (;;) {
            bool bad = false;
            #pragma unroll
            for (int k = 0; k < 4; ++k) {
                unsigned m = ((pv[k][0]^tgpat)|(pv[k][1]^tgpat)
                             |(pv[k][2]^tgpat)|(pv[k][3]^tgpat)) & 0x00010001u;
                if (m) { pv[k] = hb4[(size_t)k*32]; bad = true; }
            }
            if (!bad) break;
            __builtin_amdgcn_s_sleep(1);
        }
        #pragma unroll
        for (int k = 0; k < 4; ++k) {
            u32x4 vv = pv[k] & 0xFFFEFFFEu;   // clear tag bits -> valid fp16 pairs
            *(u32x4*)&hl[(size_t)rr*HL_STRIDE + (size_t)k*256 + (size_t)lane32*8] = vv;
        }
        bar_lds();   // B3: hl ready for next step's MFMA
    }

    // chunk-carry state
    if (t1 < T_STEPS) {
        if (valid) cstate[(size_t)batch*HDIM + hcg] = c;
        if (lid == 0 && w == 0 && q == 0 && valid) mustate[batch] = mu_own;
    }
}

extern "C" void kernel_launch(void* const* d_in, const int* in_sizes, int n_in,
                              void* d_out, int out_size, void* d_ws, size_t ws_size,
                              hipStream_t stream) {
    (void)in_sizes; (void)n_in;
    const float* series = (const float*)d_in[0];
    const float* W0  = (const float*)d_in[1];
    const float* b0  = (const float*)d_in[2];
    const float* g0  = (const float*)d_in[3];
    const float* be0 = (const float*)d_in[4];
    const float* W1  = (const float*)d_in[5];
    const float* b1  = (const float*)d_in[6];
    const float* g1  = (const float*)d_in[7];
    const float* be1 = (const float*)d_in[8];
    float* out = (float*)d_out;
    unsigned char* ws = (unsigned char*)d_ws;

    int cT = 0;
    const int cands[4] = {256, 128, 64, 32};
    for (int i = 0; i < 4; ++i) {
        size_t need = (size_t)cands[i]*32*ZDIM*4 + 2*SZ_HSEQ + SZ_TAIL;
        if (need <= ws_size) { cT = cands[i]; break; }
    }
    if (cT == 0) {
        (void)hipMemsetAsync(d_out, 0, (size_t)out_size * sizeof(float), stream);
        return;
    }
    const size_t sz_xp = (size_t)cT*32*ZDIM*4;
    unsigned char* p = ws;
    float*    xp      = (float*)p;    p += sz_xp;
    bf16_t*   hseq_hi = (bf16_t*)p;   p += SZ_HSEQ;
    bf16_t*   hseq_lo = (bf16_t*)p;   p += SZ_HSEQ;
    unsigned* Hbuf    = (unsigned*)p; p += SZ_HBUF;   // Hbuf+Sp contiguous for init_fill
    unsigned* Sp      = (unsigned*)p; p += SZ_SP;
    bf16_t*   hst_hi  = (bf16_t*)p;   p += SZ_HST;
    bf16_t*   hst_lo  = (bf16_t*)p;   p += SZ_HST;
    float*    cstate  = (float*)p;    p += SZ_CST;
    float*    mustate = (float*)p;

    (void)hipFuncSetAttribute((const void*)scan_kernel,
                              hipFuncAttributeMaxDynamicSharedMemorySize, SCAN_LDS);

    const int nch = T_STEPS / cT;
    const int gemm_grid = (cT*32/64) * (ZDIM/64);

    // ---- layer 0 ----
    init_fill<<<(FILL_WORDS + 255)/256, 256, 0, stream>>>(Hbuf, FILL_WORDS);
    for (int ci = 0; ci < nch; ++ci) {
        int t0 = ci*cT, t1 = t0 + cT;
        gemm_xp<256, 0><<<gemm_grid, 256, 0, stream>>>(
            series, nullptr, nullptr, W0, b0, xp, t0);
        scan_kernel<<<256, 256, SCAN_LDS, stream>>>(
            W0 + (size_t)256*ZDIM, xp, g0, be0, Hbuf, Sp,
            hseq_hi, hseq_lo, nullptr, hst_hi, hst_lo, cstate, mustate, t0, t1);
    }
    // ---- layer 1 (re-poison kills cross-layer tag aliasing at t=2,3) ----
    init_fill<<<(FILL_WORDS + 255)/256, 256, 0, stream>>>(Hbuf, FILL_WORDS);
    for (int ci = 0; ci < nch; ++ci) {
        int t0 = ci*cT, t1 = t0 + cT;
        gemm_xp<1024, 1><<<gemm_grid, 256, 0, stream>>>(
            nullptr, hseq_hi, hseq_lo, W1, b1, xp, t0);
        scan_kernel<<<256, 256, SCAN_LDS, stream>>>(
            W1 + (size_t)1024*ZDIM, xp, g1, be1, Hbuf, Sp,
            nullptr, nullptr, out, hst_hi, hst_lo, cstate, mustate, t0, t1);
    }
}